// Round 7
// baseline (2289.510 us; speedup 1.0000x reference)
//
#include <hip/hip_runtime.h>
#include <stdint.h>

// ---------------- problem constants ----------------
#define EMBD   256
#define HID    512
#define KTOT   768            // EMB + HID
#define NCLS   50257
#define STEPS  512

// ---------------- persistent-kernel partition ----------------
#define NGROUP 8               // batch groups
#define GB     8               // batches per group
#define BPG    32              // blocks per group (hidden split)
#define HS     16              // hidden units per block -> 64 gate rows
#define UPITCH 776             // u row pitch in bf16 elems (768 + 8 pad)
#define RP     129             // red tile pitch in floats (129 mod 32 = 1 -> conflict-free)

typedef float f32x4  __attribute__((ext_vector_type(4)));
typedef short bf16x8 __attribute__((ext_vector_type(8)));
typedef unsigned long long u64;

__device__ __forceinline__ unsigned bf16_rne(float f) {
  unsigned u = __float_as_uint(f);
  return (u + 0x7FFFu + ((u >> 16) & 1u)) >> 16;
}
__device__ __forceinline__ float bf16_to_f32(unsigned b) {
  return __uint_as_float(b << 16);
}

// ============ kernel 1: embedding gather + bf16 hi/lo pack ============
__global__ void emb_prep(const int* __restrict__ x, const float* __restrict__ emb,
                         unsigned* __restrict__ emb_hl) {
  int base = blockIdx.x * 4;
  int k = threadIdx.x;
  for (int it = 0; it < 4; ++it) {
    int tok = base + it;
    int id = x[tok];
    float w = emb[(size_t)id * EMBD + k];
    unsigned hb = bf16_rne(w);
    unsigned lb = bf16_rne(w - bf16_to_f32(hb));
    emb_hl[(size_t)tok * EMBD + k] = hb | (lb << 16);
  }
}

// ============ kernel 2: persistent LSTM recurrence ============
// 256 blocks (cooperative), 512 thr. group g = blockIdx&7, slice s = blockIdx>>3.
// h exchange: SELF-SYNCHRONIZING u64 {tag=step+1 | hi|lo} words, relaxed
// agent-scope 8B atomics, parity double buffer. Tag match implies validity;
// a block stores step+1 only after consuming all of step, which proves every
// block finished reading step-1 (the data being overwritten).
// R1: coalesced polls (lane l reads unit j*64+l). Compute path below = R1
//   exactly (best measured, 1179 us).
// R7: HINT-GATED EXCHANGE. Evidence (R2/R3/R5): removing post-detect compute
//   never helps and can hurt -> the period is paced by the poll traffic
//   itself (256 blocks x 8 waves x 8 agent loads spinning on the coherent
//   fabric). Fix: writers fire one per-wave fire-and-forget atomic_add to a
//   per-writer-block counter cnt[g][s] (monotonic, 8 per step). Per reader
//   block, ONLY wave 0 (lanes<32) polls the 32 counters (1 load/lane/round,
//   2 lines, shared by the whole group -> LLC-broadcast friendly). Other
//   waves spin on an LDS flag (zero fabric traffic). When cnt[g][*] >=
//   8*step, waves issue the UNCHANGED tag-verified data loads (normally one
//   round). The counter is a pure hint: the per-word tag check remains the
//   only correctness guard, so ordering between data stores and the counter
//   RMW is irrelevant; worst case is one extra verified round.
__global__ __launch_bounds__(512, 2) void lstm_persist(
    const float* __restrict__ Ww, const float* __restrict__ Wb,
    const unsigned* __restrict__ emb_hl,
    u64* __restrict__ hbuf,
    unsigned* __restrict__ wcnt,
    unsigned short* __restrict__ h_hi, unsigned short* __restrict__ h_lo)
{
  __shared__ __align__(16) unsigned short u_hi[16 * UPITCH];
  __shared__ __align__(16) unsigned short u_lo[16 * UPITCH];
  __shared__ __align__(16) float red[32 * RP];   // [wave*4+nt][lane<32][4] padded
  __shared__ int lds_step;                       // hint flag: last step whose h is ready

  const int tid  = threadIdx.x;
  const int wave = tid >> 6;
  const int lane = tid & 63;
  const int g = blockIdx.x & 7;     // batch group 0..7  (XCD-local under rr)
  const int s = blockIdx.x >> 3;    // hidden slice 0..31

  // zero u rows once (rows 8..15 are M-padding and stay zero forever)
  for (int i = tid; i < 16 * UPITCH; i += 512) { u_hi[i] = 0; u_lo[i] = 0; }
  if (tid == 0) lds_step = -1;

  // ---- load W B-fragments into registers (one time) ----
  const int cn = lane & 15;
  const int qk = (lane >> 4) * 8;
  bf16x8 whi[3][4], wlo[3][4];
#pragma unroll
  for (int i = 0; i < 3; ++i) {
    int kt = wave * 3 + i;
    int k0 = kt * 32 + qk;
#pragma unroll
    for (int nt = 0; nt < 4; ++nt) {
      int row = nt * 512 + s * HS + cn;
      const float* src = Ww + (size_t)row * KTOT + k0;
      float4 w0 = *(const float4*)src;
      float4 w1 = *(const float4*)(src + 4);
      float wv[8] = {w0.x, w0.y, w0.z, w0.w, w1.x, w1.y, w1.z, w1.w};
#pragma unroll
      for (int j = 0; j < 8; ++j) {
        unsigned hb = bf16_rne(wv[j]);
        unsigned lb = bf16_rne(wv[j] - bf16_to_f32(hb));
        whi[i][nt][j] = (short)hb;
        wlo[i][nt][j] = (short)lb;
      }
    }
  }

  const float bias = Wb[(lane >> 4) * 512 + s * HS + (lane & 15)];

  float Cst = 0.0f;  // cell state for (batch=wave, unit=lane) on lanes<16

  const unsigned* embg = emb_hl + (size_t)(g * GB) * STEPS * EMBD;
  u64* hg = hbuf + (size_t)g * 2 * GB * HID;
  unsigned* cg = wcnt + g * 32;

  __syncthreads();

  for (int step = 0; step < STEPS; ++step) {
    // ---- stage emb (independent of h: load issued before the wait) ----
    {
      int f0 = tid * 4;
      int b = f0 >> 8, k0 = f0 & 255;
      uint4 v = *(const uint4*)(embg + ((size_t)b * STEPS + step) * EMBD + k0);
      unsigned h01 = (v.x & 0xFFFFu) | ((v.y & 0xFFFFu) << 16);
      unsigned h23 = (v.z & 0xFFFFu) | ((v.w & 0xFFFFu) << 16);
      unsigned l01 = (v.x >> 16) | (v.y & 0xFFFF0000u);
      unsigned l23 = (v.z >> 16) | (v.w & 0xFFFF0000u);
      *(uint2*)&u_hi[b * UPITCH + k0] = make_uint2(h01, h23);
      *(uint2*)&u_lo[b * UPITCH + k0] = make_uint2(l01, l23);
    }

    // ---- hint gate: wave 0 polls 32 counters; others spin on LDS ----
    if (step > 0) {
      if (wave == 0) {
        const unsigned need = 8u * (unsigned)step;
        if (lane < 32) {
          while (__hip_atomic_load(&cg[lane], __ATOMIC_RELAXED,
                                   __HIP_MEMORY_SCOPE_AGENT) < need)
            __builtin_amdgcn_s_sleep(1);
        }
        __hip_atomic_store(&lds_step, step, __ATOMIC_RELAXED,
                           __HIP_MEMORY_SCOPE_WORKGROUP);
      } else {
        while (__hip_atomic_load(&lds_step, __ATOMIC_RELAXED,
                                 __HIP_MEMORY_SCOPE_WORKGROUP) < step)
          __builtin_amdgcn_s_sleep(1);
      }
    }

    // ---- tag-verified data load + stage h (normally exactly one round) ----
    {
      const u64* hp = hg + ((size_t)(step & 1) * GB + wave) * HID;
      u64 v[8];
      const unsigned want = (unsigned)step;
      while (true) {
        bool ok = true;
#pragma unroll
        for (int j = 0; j < 8; ++j)
          v[j] = __hip_atomic_load(&hp[j * 64 + lane], __ATOMIC_RELAXED,
                                   __HIP_MEMORY_SCOPE_AGENT);
#pragma unroll
        for (int j = 0; j < 8; ++j)
          ok &= ((unsigned)(v[j] >> 32) == want);
        if (ok) break;
        __builtin_amdgcn_s_sleep(1);
      }
#pragma unroll
      for (int j = 0; j < 8; ++j) {
        unsigned w32 = (unsigned)v[j];
        u_hi[wave * UPITCH + EMBD + j * 64 + lane] = (unsigned short)(w32 & 0xFFFFu);
        u_lo[wave * UPITCH + EMBD + j * 64 + lane] = (unsigned short)(w32 >> 16);
      }
    }
    __syncthreads();

    // ---- gates = u @ W_sliceT : MFMA, k-split 8 ways over waves ----
    f32x4 acc[4] = {{0.f,0.f,0.f,0.f},{0.f,0.f,0.f,0.f},
                    {0.f,0.f,0.f,0.f},{0.f,0.f,0.f,0.f}};
#pragma unroll
    for (int i = 0; i < 3; ++i) {
      int k0 = (wave * 3 + i) * 32 + qk;
      int m = lane & 15;
      bf16x8 ahi = *(const bf16x8*)&u_hi[m * UPITCH + k0];
      bf16x8 alo = *(const bf16x8*)&u_lo[m * UPITCH + k0];
#pragma unroll
      for (int nt = 0; nt < 4; ++nt) {
        acc[nt] = __builtin_amdgcn_mfma_f32_16x16x32_bf16(ahi, whi[i][nt], acc[nt], 0, 0, 0);
        acc[nt] = __builtin_amdgcn_mfma_f32_16x16x32_bf16(ahi, wlo[i][nt], acc[nt], 0, 0, 0);
        acc[nt] = __builtin_amdgcn_mfma_f32_16x16x32_bf16(alo, whi[i][nt], acc[nt], 0, 0, 0);
      }
    }
    // only lanes<32 hold valid rows (m=0..7); pitch 129 kills bank conflicts
    if (lane < 32) {
#pragma unroll
      for (int nt = 0; nt < 4; ++nt)
        *(f32x4*)&red[(wave * 4 + nt) * RP + lane * 4] = acc[nt];
    }
    __syncthreads();

    // ---- k-split reduction: thread owns (batch=wave, gate-row=lane) ----
    float gsum = bias;
    {
      int tq = lane >> 4;
      int rbase = ((((wave >> 2) << 4) | (lane & 15)) << 2) + (wave & 3);
#pragma unroll
      for (int w = 0; w < 8; ++w)
        gsum += red[(w * 4 + tq) * RP + rbase];
    }

    // ---- nonlinearities: lanes 0-15 f, 16-31 i, 32-47 o, 48-63 c~ ----
    float scl = (lane >= 48) ? 2.0f : 1.0f;
    float y = 1.0f / (1.0f + __expf(-gsum * scl));
    float act = (lane >= 48) ? (2.0f * y - 1.0f) : y;   // tanh via sigmoid
    float ig = __shfl(act, lane + 16);
    float og = __shfl(act, lane + 32);
    float cg_ = __shfl(act, lane + 48);
    if (lane < 16) {
      Cst = act * Cst + ig * cg_;
      float t2 = 1.0f / (1.0f + __expf(-2.0f * Cst));
      float hv = og * (2.0f * t2 - 1.0f);
      unsigned hb = bf16_rne(hv);
      unsigned lb = bf16_rne(hv - bf16_to_f32(hb));
      u64 pack = ((u64)(unsigned)(step + 1) << 32) | (u64)(hb | (lb << 16));
      __hip_atomic_store(
          &hg[((size_t)((step + 1) & 1) * GB + wave) * HID + s * HS + lane],
          pack, __ATOMIC_RELAXED, __HIP_MEMORY_SCOPE_AGENT);
      // hint: one fire-and-forget RMW per wave per step (8 per counter)
      if (lane == 0)
        __hip_atomic_fetch_add(&cg[s], 1u, __ATOMIC_RELAXED,
                               __HIP_MEMORY_SCOPE_AGENT);
      if (step == STEPS - 1) {
        int m = g * GB + wave, k = s * HS + lane;
        h_hi[m * HID + k] = (unsigned short)hb;
        h_lo[m * HID + k] = (unsigned short)lb;
      }
    }
    // no trailing barrier: next iteration's syncthreads protects LDS reuse
  }
}

// ============ kernel 3: out = h_final @ fcT + bias (MFMA hi/lo) ============
__device__ __forceinline__ void cvt8(const float4& a, const float4& b,
                                     bf16x8& hi, bf16x8& lo) {
  float v[8] = {a.x, a.y, a.z, a.w, b.x, b.y, b.z, b.w};
#pragma unroll
  for (int j = 0; j < 8; ++j) {
    unsigned hb = bf16_rne(v[j]);
    hi[j] = (short)hb;
    lo[j] = (short)bf16_rne(v[j] - bf16_to_f32(hb));
  }
}

__global__ __launch_bounds__(512) void fc_mfma(
    const unsigned short* __restrict__ h_hi, const unsigned short* __restrict__ h_lo,
    const float* __restrict__ fcw, const float* __restrict__ fcb,
    float* __restrict__ out)
{
  const int tid = threadIdx.x, wave = tid >> 6, lane = tid & 63;
  const int cn = lane & 15;
  const int qk = (lane >> 4) * 8;
  const int cls  = blockIdx.x * 128 + wave * 16 + cn;
  const int clsc = cls < NCLS ? cls : NCLS - 1;

  f32x4 acc[4] = {{0.f,0.f,0.f,0.f},{0.f,0.f,0.f,0.f},
                  {0.f,0.f,0.f,0.f},{0.f,0.f,0.f,0.f}};
#pragma unroll 2
  for (int kt = 0; kt < 16; ++kt) {
    int k0 = kt * 32 + qk;
    const float* bp = fcw + (size_t)clsc * HID + k0;
    float4 b0 = *(const float4*)bp;
    float4 b1 = *(const float4*)(bp + 4);
    bf16x8 bhi, blo;
    cvt8(b0, b1, bhi, blo);
#pragma unroll
    for (int mt = 0; mt < 4; ++mt) {
      bf16x8 ahi = *(const bf16x8*)&h_hi[(size_t)(mt * 16 + cn) * HID + k0];
      bf16x8 alo = *(const bf16x8*)&h_lo[(size_t)(mt * 16 + cn) * HID + k0];
      acc[mt] = __builtin_amdgcn_mfma_f32_16x16x32_bf16(ahi, bhi, acc[mt], 0, 0, 0);
      acc[mt] = __builtin_amdgcn_mfma_f32_16x16x32_bf16(ahi, blo, acc[mt], 0, 0, 0);
      acc[mt] = __builtin_amdgcn_mfma_f32_16x16x32_bf16(alo, bhi, acc[mt], 0, 0, 0);
    }
  }
  if (cls < NCLS) {
    float bias = fcb[cls];
#pragma unroll
    for (int mt = 0; mt < 4; ++mt)
#pragma unroll
      for (int j = 0; j < 4; ++j) {
        int m = mt * 16 + (lane >> 4) * 4 + j;
        out[(size_t)m * NCLS + cls] = acc[mt][j] + bias;
      }
  }
}

// ============ launcher ============
extern "C" void kernel_launch(void* const* d_in, const int* in_sizes, int n_in,
                              void* d_out, int out_size, void* d_ws, size_t ws_size,
                              hipStream_t stream) {
  const int*   x   = (const int*)d_in[0];
  const float* emb = (const float*)d_in[1];
  const float* Ww  = (const float*)d_in[2];
  const float* Wb  = (const float*)d_in[3];
  const float* fcw = (const float*)d_in[4];
  const float* fcb = (const float*)d_in[5];
  float* out = (float*)d_out;

  // workspace carve-up
  char* ws = (char*)d_ws;
  u64*            hbuf   = (u64*)ws;                          // 524,288 B (8g x 2slot x 8b x 512 x 8B)
  unsigned*       wcnt   = (unsigned*)(ws + 524288);          //   4,096 B (8g x 32 counters used)
  unsigned short* h_hi   = (unsigned short*)(ws + 528384);    //  65,536 B
  unsigned short* h_lo   = (unsigned short*)(ws + 528384 + 65536);
  unsigned*       emb_hl = (unsigned*)(ws + 528384 + 131072); // 33.5 MB

  // zero h exchange buffer + hint counters:
  // tag=0 == "h for step 0 valid and zero"; cnt=0 == "no step finished"
  hipMemsetAsync(hbuf, 0, 528384, stream);

  emb_prep<<<8192, 256, 0, stream>>>(x, emb, emb_hl);

  void* args[] = { (void*)&Ww, (void*)&Wb, (void*)&emb_hl,
                   (void*)&hbuf, (void*)&wcnt, (void*)&h_hi, (void*)&h_lo };
  hipLaunchCooperativeKernel((void*)lstm_persist, dim3(256), dim3(512),
                             args, 0, stream);

  fc_mfma<<<(NCLS + 127) / 128, 512, 0, stream>>>(h_hi, h_lo, fcw, fcb, out);
}

// Round 8
// 1343.846 us; speedup vs baseline: 1.7037x; 1.7037x over previous
//
#include <hip/hip_runtime.h>
#include <stdint.h>

// ---------------- problem constants ----------------
#define EMBD   256
#define HID    512
#define KTOT   768            // EMB + HID
#define NCLS   50257
#define STEPS  512

// ---------------- persistent-kernel partition ----------------
#define NGROUP 8               // batch groups
#define GB     8               // batches per group
#define BPG    32              // blocks per group (hidden split)
#define HS     16              // hidden units per block -> 64 gate rows
#define UPITCH 776             // u row pitch in bf16 elems (768 + 8 pad)
#define RP     129             // red tile pitch in floats (129 mod 32 = 1 -> conflict-free)

typedef float f32x4  __attribute__((ext_vector_type(4)));
typedef short bf16x8 __attribute__((ext_vector_type(8)));
typedef unsigned long long u64;

__device__ __forceinline__ unsigned bf16_rne(float f) {
  unsigned u = __float_as_uint(f);
  return (u + 0x7FFFu + ((u >> 16) & 1u)) >> 16;
}
__device__ __forceinline__ float bf16_to_f32(unsigned b) {
  return __uint_as_float(b << 16);
}

// ============ kernel 1: embedding gather + bf16 hi/lo pack ============
__global__ void emb_prep(const int* __restrict__ x, const float* __restrict__ emb,
                         unsigned* __restrict__ emb_hl) {
  int base = blockIdx.x * 4;
  int k = threadIdx.x;
  for (int it = 0; it < 4; ++it) {
    int tok = base + it;
    int id = x[tok];
    float w = emb[(size_t)id * EMBD + k];
    unsigned hb = bf16_rne(w);
    unsigned lb = bf16_rne(w - bf16_to_f32(hb));
    emb_hl[(size_t)tok * EMBD + k] = hb | (lb << 16);
  }
}

// ============ kernel 2: persistent LSTM recurrence ============
// 256 blocks (cooperative), 512 thr. group g = blockIdx&7, slice s = blockIdx>>3.
// h exchange: SELF-SYNCHRONIZING u64 {tag=step+1 | hi|lo} words, relaxed
// agent-scope 8B atomics, parity double buffer. Tag match implies validity;
// a block stores step+1 only after consuming all of step (barrier C orders
// every wave's staging before any wave's store), which proves every block
// finished reading step-1 -> overwriting step-1 slots is safe.
// R1: coalesced polls (lane l reads unit j*64+l). Direct all-wave polling is
//   the fastest exchange measured; R5 (sc0 L2 path) and R7 (hint gate) both
//   regressed by ADDING serial hops to the detect chain. R2/R3 showed any
//   MFMA issued before the poll delays detect (MFMA blocks its wave).
// R8: EMB REGISTER PREFETCH. In R1 the step began with the emb global load
//   and its vmcnt wait (~300-900cy, HBM/L3) serialized BEFORE the first poll
//   issue — pure dead time on the h-detect path. Now next step's emb uint4
//   is prefetched into registers right after h-staging (latency hides under
//   MFMA+reduce); at step top we write LDS from registers (~16 ds_writes,
//   no waits) and enter the poll immediately.
__global__ __launch_bounds__(512, 2) void lstm_persist(
    const float* __restrict__ Ww, const float* __restrict__ Wb,
    const unsigned* __restrict__ emb_hl,
    u64* __restrict__ hbuf,
    unsigned short* __restrict__ h_hi, unsigned short* __restrict__ h_lo)
{
  __shared__ __align__(16) unsigned short u_hi[16 * UPITCH];
  __shared__ __align__(16) unsigned short u_lo[16 * UPITCH];
  __shared__ __align__(16) float red[32 * RP];   // [wave*4+nt][lane<32][4] padded

  const int tid  = threadIdx.x;
  const int wave = tid >> 6;
  const int lane = tid & 63;
  const int g = blockIdx.x & 7;     // batch group 0..7  (XCD-local under rr)
  const int s = blockIdx.x >> 3;    // hidden slice 0..31

  // zero u rows once (rows 8..15 are M-padding and stay zero forever)
  for (int i = tid; i < 16 * UPITCH; i += 512) { u_hi[i] = 0; u_lo[i] = 0; }

  // ---- load W B-fragments into registers (one time) ----
  const int cn = lane & 15;
  const int qk = (lane >> 4) * 8;
  bf16x8 whi[3][4], wlo[3][4];
#pragma unroll
  for (int i = 0; i < 3; ++i) {
    int kt = wave * 3 + i;
    int k0 = kt * 32 + qk;
#pragma unroll
    for (int nt = 0; nt < 4; ++nt) {
      int row = nt * 512 + s * HS + cn;
      const float* src = Ww + (size_t)row * KTOT + k0;
      float4 w0 = *(const float4*)src;
      float4 w1 = *(const float4*)(src + 4);
      float wv[8] = {w0.x, w0.y, w0.z, w0.w, w1.x, w1.y, w1.z, w1.w};
#pragma unroll
      for (int j = 0; j < 8; ++j) {
        unsigned hb = bf16_rne(wv[j]);
        unsigned lb = bf16_rne(wv[j] - bf16_to_f32(hb));
        whi[i][nt][j] = (short)hb;
        wlo[i][nt][j] = (short)lb;
      }
    }
  }

  const float bias = Wb[(lane >> 4) * 512 + s * HS + (lane & 15)];

  float Cst = 0.0f;  // cell state for (batch=wave, unit=lane) on lanes<16

  const unsigned* embg = emb_hl + (size_t)(g * GB) * STEPS * EMBD;
  u64* hg = hbuf + (size_t)g * 2 * GB * HID;

  // per-thread emb prefetch pointer: thread covers batch eb, cols ek0..ek0+3
  const int ef0 = tid * 4;
  const int eb  = ef0 >> 8, ek0 = ef0 & 255;
  const unsigned* embp = embg + (size_t)eb * STEPS * EMBD + ek0;

  // prologue: prefetch step 0 into registers
  uint4 embv = *(const uint4*)embp;

  __syncthreads();

  for (int step = 0; step < STEPS; ++step) {
    // ---- stage emb from REGISTERS (no memory wait before the poll) ----
    {
      unsigned h01 = (embv.x & 0xFFFFu) | ((embv.y & 0xFFFFu) << 16);
      unsigned h23 = (embv.z & 0xFFFFu) | ((embv.w & 0xFFFFu) << 16);
      unsigned l01 = (embv.x >> 16) | (embv.y & 0xFFFF0000u);
      unsigned l23 = (embv.z >> 16) | (embv.w & 0xFFFF0000u);
      *(uint2*)&u_hi[eb * UPITCH + ek0] = make_uint2(h01, h23);
      *(uint2*)&u_lo[eb * UPITCH + ek0] = make_uint2(l01, l23);
    }
    // ---- poll + stage h: wave w handles batch w (coalesced, 8B lane stride) ----
    {
      const u64* hp = hg + ((size_t)(step & 1) * GB + wave) * HID;
      u64 v[8];
      const unsigned want = (unsigned)step;
      while (true) {
        bool ok = true;
#pragma unroll
        for (int j = 0; j < 8; ++j)
          v[j] = __hip_atomic_load(&hp[j * 64 + lane], __ATOMIC_RELAXED,
                                   __HIP_MEMORY_SCOPE_AGENT);
#pragma unroll
        for (int j = 0; j < 8; ++j)
          ok &= ((unsigned)(v[j] >> 32) == want);
        if (ok) break;
        __builtin_amdgcn_s_sleep(1);
      }
#pragma unroll
      for (int j = 0; j < 8; ++j) {
        unsigned w32 = (unsigned)v[j];
        u_hi[wave * UPITCH + EMBD + j * 64 + lane] = (unsigned short)(w32 & 0xFFFFu);
        u_lo[wave * UPITCH + EMBD + j * 64 + lane] = (unsigned short)(w32 >> 16);
      }
    }
    // ---- issue next step's emb prefetch (latency hides under MFMA+reduce) ----
    {
      int nstep = (step + 1 < STEPS) ? step + 1 : step;
      embv = *(const uint4*)(embp + (size_t)nstep * EMBD);
    }
    __syncthreads();

    // ---- gates = u @ W_sliceT : MFMA, k-split 8 ways over waves ----
    f32x4 acc[4] = {{0.f,0.f,0.f,0.f},{0.f,0.f,0.f,0.f},
                    {0.f,0.f,0.f,0.f},{0.f,0.f,0.f,0.f}};
#pragma unroll
    for (int i = 0; i < 3; ++i) {
      int k0 = (wave * 3 + i) * 32 + qk;
      int m = lane & 15;
      bf16x8 ahi = *(const bf16x8*)&u_hi[m * UPITCH + k0];
      bf16x8 alo = *(const bf16x8*)&u_lo[m * UPITCH + k0];
#pragma unroll
      for (int nt = 0; nt < 4; ++nt) {
        acc[nt] = __builtin_amdgcn_mfma_f32_16x16x32_bf16(ahi, whi[i][nt], acc[nt], 0, 0, 0);
        acc[nt] = __builtin_amdgcn_mfma_f32_16x16x32_bf16(ahi, wlo[i][nt], acc[nt], 0, 0, 0);
        acc[nt] = __builtin_amdgcn_mfma_f32_16x16x32_bf16(alo, whi[i][nt], acc[nt], 0, 0, 0);
      }
    }
    // only lanes<32 hold valid rows (m=0..7); pitch 129 kills bank conflicts
    if (lane < 32) {
#pragma unroll
      for (int nt = 0; nt < 4; ++nt)
        *(f32x4*)&red[(wave * 4 + nt) * RP + lane * 4] = acc[nt];
    }
    __syncthreads();

    // ---- k-split reduction: thread owns (batch=wave, gate-row=lane) ----
    float gsum = bias;
    {
      int tq = lane >> 4;
      int rbase = ((((wave >> 2) << 4) | (lane & 15)) << 2) + (wave & 3);
#pragma unroll
      for (int w = 0; w < 8; ++w)
        gsum += red[(w * 4 + tq) * RP + rbase];
    }

    // ---- nonlinearities: lanes 0-15 f, 16-31 i, 32-47 o, 48-63 c~ ----
    float scl = (lane >= 48) ? 2.0f : 1.0f;
    float y = 1.0f / (1.0f + __expf(-gsum * scl));
    float act = (lane >= 48) ? (2.0f * y - 1.0f) : y;   // tanh via sigmoid
    float ig = __shfl(act, lane + 16);
    float og = __shfl(act, lane + 32);
    float cg_ = __shfl(act, lane + 48);
    if (lane < 16) {
      Cst = act * Cst + ig * cg_;
      float t2 = 1.0f / (1.0f + __expf(-2.0f * Cst));
      float hv = og * (2.0f * t2 - 1.0f);
      unsigned hb = bf16_rne(hv);
      unsigned lb = bf16_rne(hv - bf16_to_f32(hb));
      u64 pack = ((u64)(unsigned)(step + 1) << 32) | (u64)(hb | (lb << 16));
      __hip_atomic_store(
          &hg[((size_t)((step + 1) & 1) * GB + wave) * HID + s * HS + lane],
          pack, __ATOMIC_RELAXED, __HIP_MEMORY_SCOPE_AGENT);
      if (step == STEPS - 1) {
        int m = g * GB + wave, k = s * HS + lane;
        h_hi[m * HID + k] = (unsigned short)hb;
        h_lo[m * HID + k] = (unsigned short)lb;
      }
    }
    // no trailing barrier: barrier C already ordered all MFMA reads of this
    // step's u before any wave proceeds, so next step's staging is safe.
  }
}

// ============ kernel 3: out = h_final @ fcT + bias (MFMA hi/lo) ============
__device__ __forceinline__ void cvt8(const float4& a, const float4& b,
                                     bf16x8& hi, bf16x8& lo) {
  float v[8] = {a.x, a.y, a.z, a.w, b.x, b.y, b.z, b.w};
#pragma unroll
  for (int j = 0; j < 8; ++j) {
    unsigned hb = bf16_rne(v[j]);
    hi[j] = (short)hb;
    lo[j] = (short)bf16_rne(v[j] - bf16_to_f32(hb));
  }
}

__global__ __launch_bounds__(512) void fc_mfma(
    const unsigned short* __restrict__ h_hi, const unsigned short* __restrict__ h_lo,
    const float* __restrict__ fcw, const float* __restrict__ fcb,
    float* __restrict__ out)
{
  const int tid = threadIdx.x, wave = tid >> 6, lane = tid & 63;
  const int cn = lane & 15;
  const int qk = (lane >> 4) * 8;
  const int cls  = blockIdx.x * 128 + wave * 16 + cn;
  const int clsc = cls < NCLS ? cls : NCLS - 1;

  f32x4 acc[4] = {{0.f,0.f,0.f,0.f},{0.f,0.f,0.f,0.f},
                  {0.f,0.f,0.f,0.f},{0.f,0.f,0.f,0.f}};
#pragma unroll 2
  for (int kt = 0; kt < 16; ++kt) {
    int k0 = kt * 32 + qk;
    const float* bp = fcw + (size_t)clsc * HID + k0;
    float4 b0 = *(const float4*)bp;
    float4 b1 = *(const float4*)(bp + 4);
    bf16x8 bhi, blo;
    cvt8(b0, b1, bhi, blo);
#pragma unroll
    for (int mt = 0; mt < 4; ++mt) {
      bf16x8 ahi = *(const bf16x8*)&h_hi[(size_t)(mt * 16 + cn) * HID + k0];
      bf16x8 alo = *(const bf16x8*)&h_lo[(size_t)(mt * 16 + cn) * HID + k0];
      acc[mt] = __builtin_amdgcn_mfma_f32_16x16x32_bf16(ahi, bhi, acc[mt], 0, 0, 0);
      acc[mt] = __builtin_amdgcn_mfma_f32_16x16x32_bf16(ahi, blo, acc[mt], 0, 0, 0);
      acc[mt] = __builtin_amdgcn_mfma_f32_16x16x32_bf16(alo, bhi, acc[mt], 0, 0, 0);
    }
  }
  if (cls < NCLS) {
    float bias = fcb[cls];
#pragma unroll
    for (int mt = 0; mt < 4; ++mt)
#pragma unroll
      for (int j = 0; j < 4; ++j) {
        int m = mt * 16 + (lane >> 4) * 4 + j;
        out[(size_t)m * NCLS + cls] = acc[mt][j] + bias;
      }
  }
}

// ============ launcher ============
extern "C" void kernel_launch(void* const* d_in, const int* in_sizes, int n_in,
                              void* d_out, int out_size, void* d_ws, size_t ws_size,
                              hipStream_t stream) {
  const int*   x   = (const int*)d_in[0];
  const float* emb = (const float*)d_in[1];
  const float* Ww  = (const float*)d_in[2];
  const float* Wb  = (const float*)d_in[3];
  const float* fcw = (const float*)d_in[4];
  const float* fcb = (const float*)d_in[5];
  float* out = (float*)d_out;

  // workspace carve-up
  char* ws = (char*)d_ws;
  u64*            hbuf   = (u64*)ws;                          // 524,288 B (8g x 2slot x 8b x 512 x 8B)
  unsigned short* h_hi   = (unsigned short*)(ws + 524288);    //  65,536 B
  unsigned short* h_lo   = (unsigned short*)(ws + 524288 + 65536);
  unsigned*       emb_hl = (unsigned*)(ws + 524288 + 131072); // 33.5 MB

  // zero h exchange buffer: tag=0 == "h for step 0 valid and zero"
  hipMemsetAsync(hbuf, 0, 524288, stream);

  emb_prep<<<8192, 256, 0, stream>>>(x, emb, emb_hl);

  void* args[] = { (void*)&Ww, (void*)&Wb, (void*)&emb_hl,
                   (void*)&hbuf, (void*)&h_hi, (void*)&h_lo };
  hipLaunchCooperativeKernel((void*)lstm_persist, dim3(256), dim3(512),
                             args, 0, stream);

  fc_mfma<<<(NCLS + 127) / 128, 512, 0, stream>>>(h_hi, h_lo, fcw, fcb, out);
}